// Round 1
// 698.826 us; speedup vs baseline: 1.4333x; 1.4333x over previous
//
#include <hip/hip_runtime.h>
#include <hip/hip_bf16.h>
#include <math.h>

using short8   = __attribute__((ext_vector_type(8))) short;
using floatx4  = __attribute__((ext_vector_type(4))) float;
using floatx16 = __attribute__((ext_vector_type(16))) float;

#define B_N  32
#define S_N  1026
#define R_N  256
#define H_N  1024
#define NH_N 16
#define HD_N 64
#define SP_N 1088          // padded S for V^T rows: 17 * 64, pad cols zeroed once
#define KTILES 17          // SP_N / 64

__device__ __forceinline__ float bf2f(__hip_bfloat16 x) { return __bfloat162float(x); }
__device__ __forceinline__ __hip_bfloat16 f2bf(float x) { return __float2bfloat16(x); }

__device__ __forceinline__ float fast_exp2(float x) {
#if __has_builtin(__builtin_amdgcn_exp2f)
    return __builtin_amdgcn_exp2f(x);
#else
    return exp2f(x);
#endif
}

// pack two f32 -> one u32 of two bf16 (RNE), single instruction
__device__ __forceinline__ unsigned cvtpk(float lo, float hi_) {
    unsigned r;
    asm("v_cvt_pk_bf16_f32 %0, %1, %2" : "=v"(r) : "v"(lo), "v"(hi_));
    return r;
}

// async global->LDS, 16B per lane; LDS dest = uniform base + lane*16
__device__ __forceinline__ void gl_lds16(const void* g, void* l) {
    __builtin_amdgcn_global_load_lds(
        (const __attribute__((address_space(1))) unsigned int*)g,
        (__attribute__((address_space(3))) unsigned int*)l, 16, 0, 0);
}

// convert 8 fp32 (two float4) -> short8 of bf16
__device__ __forceinline__ short8 cvt8(const float* __restrict__ p) {
    floatx4 a = *(const floatx4*)p;
    floatx4 b = *(const floatx4*)(p + 4);
    short8 o;
    __hip_bfloat16* op = (__hip_bfloat16*)&o;
    op[0] = f2bf(a[0]); op[1] = f2bf(a[1]); op[2] = f2bf(a[2]); op[3] = f2bf(a[3]);
    op[4] = f2bf(b[0]); op[5] = f2bf(b[1]); op[6] = f2bf(b[2]); op[7] = f2bf(b[3]);
    return o;
}

// ---------------- transpose + downcast: out[n*K + k] = bf16(in[k*N + n]) ----------------
__global__ void transpose_kernel(const float* __restrict__ in,
                                 __hip_bfloat16* __restrict__ out,
                                 int K, int N) {
    int idx = blockIdx.x * 256 + threadIdx.x;
    if (idx < K * N) {
        int n = idx % N, k = idx / N;
        out[n * K + k] = f2bf(in[idx]);
    }
}

// ---------------- zero the V^T pad columns [S_N, SP_N) once per launch ----------------
__global__ void padv_kernel(__hip_bfloat16* __restrict__ Vt, int total) {
    int idx = blockIdx.x * 256 + threadIdx.x;
    if (idx < total) {
        int p  = idx % (SP_N - S_N);
        int rd = idx / (SP_N - S_N);          // row index over C*NH*HD d-rows
        Vt[(size_t)rd * SP_N + S_N + p] = f2bf(0.f);
    }
}

// ---------------- up-projection, 128x128 tile: C[m,n] = oscale*(X[m,:] @ W[:,n] + bias[n])
// MODE 0: out[((bl*NH + h)*S + s)*HD + d]    (Q, K layout)
// MODE 1: out[((bl*NH + h)*HD + d)*SP + s]   (V transposed layout, padded rows)
template <int MODE>
__global__ __launch_bounds__(256) void proj_kernel(
    const float* __restrict__ X,              // [Mc, R_N] fp32
    const __hip_bfloat16* __restrict__ WT,    // [H_N, R_N]  (W transposed, bf16)
    const float* __restrict__ bias,           // [H_N] fp32
    __hip_bfloat16* __restrict__ out, int Mc, float oscale) {
    __shared__ __hip_bfloat16 As[128][40];
    __shared__ __hip_bfloat16 Bs[128][40];
    const int tid  = threadIdx.x;
    const int wave = tid >> 6, lane = tid & 63;
    const int quad = lane >> 4, l16 = lane & 15;
    const int tm = blockIdx.x * 128, tn = blockIdx.y * 128;
    const int mw = (wave >> 1) * 64, nw = (wave & 1) * 64;

    floatx4 acc[4][4] = {};

    for (int kk = 0; kk < R_N; kk += 32) {
        __syncthreads();
#pragma unroll
        for (int i = 0; i < 2; ++i) {
            int g = tid + i * 256;           // 0..511 groups of 8
            int row = g >> 2, cb = (g & 3) * 8;
            int gm = tm + row;
            short8 av = {0, 0, 0, 0, 0, 0, 0, 0};
            if (gm < Mc) av = cvt8(X + (size_t)gm * R_N + kk + cb);
            *(short8*)&As[row][cb] = av;
            *(short8*)&Bs[row][cb] = *(const short8*)(WT + (size_t)(tn + row) * R_N + kk + cb);
        }
        __syncthreads();
        short8 af[4], bfr[4];
#pragma unroll
        for (int mb = 0; mb < 4; ++mb) af[mb]  = *(short8*)&As[mw + mb * 16 + l16][quad * 8];
#pragma unroll
        for (int nb = 0; nb < 4; ++nb) bfr[nb] = *(short8*)&Bs[nw + nb * 16 + l16][quad * 8];
#pragma unroll
        for (int mb = 0; mb < 4; ++mb)
#pragma unroll
            for (int nb = 0; nb < 4; ++nb) {
                if (MODE == 0)
                    acc[mb][nb] = __builtin_amdgcn_mfma_f32_16x16x32_bf16(af[mb], bfr[nb], acc[mb][nb], 0, 0, 0);
                else  // transposed product: C rows = n, cols = m (coalesced V^T store)
                    acc[mb][nb] = __builtin_amdgcn_mfma_f32_16x16x32_bf16(bfr[nb], af[mb], acc[mb][nb], 0, 0, 0);
            }
    }

#pragma unroll
    for (int mb = 0; mb < 4; ++mb)
#pragma unroll
        for (int nb = 0; nb < 4; ++nb)
#pragma unroll
            for (int r = 0; r < 4; ++r) {
                int m, n;
                if (MODE == 0) { m = tm + mw + mb * 16 + quad * 4 + r; n = tn + nw + nb * 16 + l16; }
                else           { n = tn + nw + nb * 16 + quad * 4 + r; m = tm + mw + mb * 16 + l16; }
                if (m >= Mc) continue;
                float v = oscale * (acc[mb][nb][r] + bias[n]);
                int bl = m / S_N, s = m - bl * S_N;
                int h = n >> 6, d = n & 63;
                size_t off = (MODE == 0)
                    ? ((size_t)((bl * NH_N + h) * S_N + s)) * HD_N + d
                    : ((size_t)((bl * NH_N + h) * HD_N + d)) * SP_N + s;
                out[off] = f2bf(v);
            }
}

// ---------------- flash attention: swapped QK^T (32x32x16), in-register softmax --------
// Per block: 4 waves x 32 q-rows = 128 q rows. K/V tiles (64 keys) double-buffered in
// XOR-swizzled LDS, staged by global_load_lds with pre-swizzled global source.
// Softmax is no-max (scores provably bounded); P repack to MFMA A-frags is fully
// in-register via v_cvt_pk_bf16_f32 + v_permlane32_swap_b32 (no P LDS buffer).
__global__ __launch_bounds__(256, 3) void attn_kernel(
    const __hip_bfloat16* __restrict__ Qh,  // [C*NH, S, HD]  (pre-scaled by log2e/8)
    const __hip_bfloat16* __restrict__ Kh,  // [C*NH, S, HD]
    const __hip_bfloat16* __restrict__ Vt,  // [C*NH, HD, SP] (pad cols zeroed)
    __hip_bfloat16* __restrict__ ctx) {     // [C, S, NH*HD]
    __shared__ __hip_bfloat16 Kl[2][64][64];   // [buf][key][d], chunk^=(key&7)
    __shared__ __hip_bfloat16 Vl[2][64][64];   // [buf][d][key], chunk^=(d&7)

    const int bh  = blockIdx.x;
    const int q0  = blockIdx.y * 128;
    const int tid = threadIdx.x;
    const int wave = tid >> 6, lane = tid & 63;
    const int c = lane & 31, hi = lane >> 5, c7 = c & 7;
    const size_t base  = (size_t)bh * S_N * HD_N;
    const size_t vbase = (size_t)bh * HD_N * SP_N;

    // staging lane constants: lane covers (row lr, chunk lane&7) of an 8-row slab
    const int lr = lane >> 3;          // 0..7
    const int sc = (lane & 7) ^ lr;    // pre-swizzled source chunk ((row&7)==lr)

    // ---- Q B-frags in registers: lane holds Q[q0+wave*32+c][16*i + 8*hi + j] ----
    short8 qf[4];
    {
        int qrow = q0 + wave * 32 + c;
        if (qrow > S_N - 1) qrow = S_N - 1;            // dup row; outputs guarded
        const __hip_bfloat16* qp = Qh + base + (size_t)qrow * HD_N + hi * 8;
#pragma unroll
        for (int i = 0; i < 4; ++i) qf[i] = *(const short8*)(qp + 16 * i);
    }

    floatx16 oacc[2] = {};   // O[q (regs)][d = 32*db + c]
    float lsum = 0.f;        // partial row-sum for q=c (this hi-half's keys)

    auto stage = [&](int bb, int kt) {
#pragma unroll
        for (int j = 0; j < 2; ++j) {
            int r = 16 * wave + 8 * j + lr;            // tile row 0..63
            int krow = kt + r;
            if (krow > S_N - 1) krow = S_N - 1;        // dup; masked by key index
            gl_lds16(Kh + base + (size_t)krow * HD_N + sc * 8,
                     &Kl[bb][16 * wave + 8 * j][0]);
            gl_lds16(Vt + vbase + (size_t)r * SP_N + kt + sc * 8,
                     &Vl[bb][16 * wave + 8 * j][0]);
        }
    };

    stage(0, 0);
    __syncthreads();                                    // implies vmcnt(0) drain

    int bb = 0;
    for (int t = 0; t < KTILES; ++t) {
        const int kt = t * 64;
        if (t + 1 < KTILES) stage(bb ^ 1, kt + 64);     // prefetch next tile
        const bool last = (kt + 64 > S_N);

        short8 pa[2][2];                                // P A-frags [sub][16-key step]
#pragma unroll
        for (int sub = 0; sub < 2; ++sub) {
            // S^T = K_tile(32) x Q^T: lane col = q (=c), regs = key rows
            floatx16 sacc = {};
#pragma unroll
            for (int i = 0; i < 4; ++i) {
                short8 kf = *(const short8*)&Kl[bb][32 * sub + c][(((2 * i + hi) ^ c7) << 3)];
                sacc = __builtin_amdgcn_mfma_f32_32x32x16_bf16(kf, qf[i], sacc, 0, 0, 0);
            }
            float ps[16];
            if (!last) {
#pragma unroll
                for (int r = 0; r < 16; ++r) ps[r] = fast_exp2(sacc[r]);
            } else {
#pragma unroll
                for (int r = 0; r < 16; ++r) {
                    int key = kt + 32 * sub + (r & 3) + 8 * (r >> 2) + 4 * hi;
                    ps[r] = (key < S_N) ? fast_exp2(sacc[r]) : 0.f;
                }
            }
#pragma unroll
            for (int r = 0; r < 16; ++r) lsum += ps[r];
            // in-register repack: reg r holds key (r&3)+8*(r>>2)+4*hi; PV A-frag
            // needs keys 8*hi+j per 16-key step -> pair-pack + lane<->lane+32 swap
#pragma unroll
            for (int step = 0; step < 2; ++step) {
                unsigned w0 = cvtpk(ps[8 * step + 0], ps[8 * step + 1]);
                unsigned w1 = cvtpk(ps[8 * step + 2], ps[8 * step + 3]);
                unsigned w2 = cvtpk(ps[8 * step + 4], ps[8 * step + 5]);
                unsigned w3 = cvtpk(ps[8 * step + 6], ps[8 * step + 7]);
                asm("v_permlane32_swap_b32 %0, %1" : "+v"(w0), "+v"(w2));
                asm("v_permlane32_swap_b32 %0, %1" : "+v"(w1), "+v"(w3));
                union { unsigned u[4]; short8 s; } fu;
                fu.u[0] = w0; fu.u[1] = w1; fu.u[2] = w2; fu.u[3] = w3;
                pa[sub][step] = fu.s;
            }
        }

        // O += P @ V  (B-frag: V[key][d], col = d = 32*db + c)
#pragma unroll
        for (int db = 0; db < 2; ++db)
#pragma unroll
            for (int sub = 0; sub < 2; ++sub)
#pragma unroll
                for (int step = 0; step < 2; ++step) {
                    short8 vf = *(const short8*)
                        &Vl[bb][32 * db + c][((((sub * 2 + step) * 2 + hi) ^ c7) << 3)];
                    oacc[db] = __builtin_amdgcn_mfma_f32_32x32x16_bf16(pa[sub][step], vf, oacc[db], 0, 0, 0);
                }

        __syncthreads();    // prefetch landed (vmcnt0) + all waves done with buf bb
        bb ^= 1;
    }

    // combine the two hi-halves' partial sums; reciprocal once per q-row
    lsum += __shfl_xor(lsum, 32);
    float rs = 1.0f / lsum;

    const int bl = bh / NH_N, h = bh - bl * NH_N;
    const int srow0 = q0 + wave * 32;
#pragma unroll
    for (int r = 0; r < 16; ++r) {
        int q = (r & 3) + 8 * (r >> 2) + 4 * hi;       // O row of reg r
        float rr = __shfl(rs, q, 32);                  // rs lives at lane c==q (both halves)
        int s = srow0 + q;
        if (s < S_N) {
            size_t o = ((size_t)(bl * S_N + s)) * H_N + h * HD_N + c;
            ctx[o]      = f2bf(oacc[0][r] * rr);
            ctx[o + 32] = f2bf(oacc[1][r] * rr);
        }
    }
}

// ---------------- down-projection + exact gelu (fp32 out) ----------------
__global__ __launch_bounds__(256) void dproj_kernel(
    const __hip_bfloat16* __restrict__ X,    // ctx [Mc, H_N]
    const __hip_bfloat16* __restrict__ WT,   // WoT [R_N, H_N]
    float* __restrict__ out,                 // [Mc, R_N] fp32
    int Mc) {
    __shared__ __hip_bfloat16 As[64][40];
    __shared__ __hip_bfloat16 Bs[64][40];
    const int tid  = threadIdx.x;
    const int wave = tid >> 6, lane = tid & 63;
    const int quad = lane >> 4, l16 = lane & 15;
    const int tm = blockIdx.x * 64, tn = blockIdx.y * 64;
    const int mw = (wave >> 1) * 32, nw = (wave & 1) * 32;
    const int srow = tid >> 2, skb = (tid & 3) * 8;

    floatx4 acc[2][2] = {};

    for (int kk = 0; kk < H_N; kk += 32) {
        __syncthreads();
        {
            int gm = tm + srow;
            short8 av = {0, 0, 0, 0, 0, 0, 0, 0};
            if (gm < Mc) av = *(const short8*)(X + (size_t)gm * H_N + kk + skb);
            *(short8*)&As[srow][skb] = av;
            *(short8*)&Bs[srow][skb] = *(const short8*)(WT + (size_t)(tn + srow) * H_N + kk + skb);
        }
        __syncthreads();
        short8 af[2], bfr[2];
        af[0]  = *(short8*)&As[mw + l16][quad * 8];
        af[1]  = *(short8*)&As[mw + 16 + l16][quad * 8];
        bfr[0] = *(short8*)&Bs[nw + l16][quad * 8];
        bfr[1] = *(short8*)&Bs[nw + 16 + l16][quad * 8];
#pragma unroll
        for (int mb = 0; mb < 2; ++mb)
#pragma unroll
            for (int nb = 0; nb < 2; ++nb)
                acc[mb][nb] = __builtin_amdgcn_mfma_f32_16x16x32_bf16(af[mb], bfr[nb], acc[mb][nb], 0, 0, 0);
    }

#pragma unroll
    for (int mb = 0; mb < 2; ++mb)
#pragma unroll
        for (int nb = 0; nb < 2; ++nb)
#pragma unroll
            for (int r = 0; r < 4; ++r) {
                int m = tm + mw + mb * 16 + quad * 4 + r;
                int n = tn + nw + nb * 16 + l16;
                if (m >= Mc) continue;
                float x = acc[mb][nb][r];
                float g = 0.5f * x * (1.0f + erff(x * 0.70710678118654752f));
                out[(size_t)m * R_N + n] = g;
            }
}

extern "C" void kernel_launch(void* const* d_in, const int* in_sizes, int n_in,
                              void* d_out, int out_size, void* d_ws, size_t ws_size,
                              hipStream_t stream) {
    const float* q_low = (const float*)d_in[0];
    const float* k_low = (const float*)d_in[1];
    const float* v_low = (const float*)d_in[2];
    const float* Wq    = (const float*)d_in[3];
    const float* bq    = (const float*)d_in[4];
    const float* Wk    = (const float*)d_in[5];
    const float* bk    = (const float*)d_in[6];
    const float* Wv    = (const float*)d_in[7];
    const float* bv    = (const float*)d_in[8];
    const float* Wo    = (const float*)d_in[9];
    float* out = (float*)d_out;
    (void)in_sizes; (void)n_in; (void)out_size;

    const float QSCALE = 0.125f * 1.44269504088896f;   // log2(e)/sqrt(HD)
    const size_t SZ_W = (size_t)H_N * R_N * 2;

    int C = 32;
    while (C > 1) {
        size_t qk = (size_t)C * NH_N * S_N * HD_N * 2;
        size_t vv = (size_t)C * NH_N * HD_N * SP_N * 2;
        size_t cx = (size_t)C * S_N * H_N * 2;
        if (4 * SZ_W + 2 * qk + vv + cx <= ws_size) break;
        C >>= 1;
    }

    char* ws = (char*)d_ws;
    const size_t SZ_QK = (size_t)C * NH_N * S_N * HD_N * 2;
    const size_t SZ_V  = (size_t)C * NH_N * HD_N * SP_N * 2;
    __hip_bfloat16* WqT = (__hip_bfloat16*)(ws);
    __hip_bfloat16* WkT = (__hip_bfloat16*)(ws + SZ_W);
    __hip_bfloat16* WvT = (__hip_bfloat16*)(ws + 2 * SZ_W);
    __hip_bfloat16* WoT = (__hip_bfloat16*)(ws + 3 * SZ_W);
    __hip_bfloat16* Qc  = (__hip_bfloat16*)(ws + 4 * SZ_W);
    __hip_bfloat16* Kc  = (__hip_bfloat16*)(ws + 4 * SZ_W + SZ_QK);
    __hip_bfloat16* Vc  = (__hip_bfloat16*)(ws + 4 * SZ_W + 2 * SZ_QK);
    __hip_bfloat16* ctc = (__hip_bfloat16*)(ws + 4 * SZ_W + 2 * SZ_QK + SZ_V);

    transpose_kernel<<<(R_N * H_N + 255) / 256, 256, 0, stream>>>(Wq, WqT, R_N, H_N);
    transpose_kernel<<<(R_N * H_N + 255) / 256, 256, 0, stream>>>(Wk, WkT, R_N, H_N);
    transpose_kernel<<<(R_N * H_N + 255) / 256, 256, 0, stream>>>(Wv, WvT, R_N, H_N);
    transpose_kernel<<<(H_N * R_N + 255) / 256, 256, 0, stream>>>(Wo, WoT, H_N, R_N);

    // zero V^T pad columns once (Vc reused across chunks; proj never touches them)
    {
        int total = C * NH_N * HD_N * (SP_N - S_N);
        padv_kernel<<<(total + 255) / 256, 256, 0, stream>>>(Vc, total);
    }

    for (int c0 = 0; c0 < B_N; c0 += C) {
        const int Mc = C * S_N;
        const size_t xoff = (size_t)c0 * S_N * R_N;
        dim3 pg((Mc + 127) / 128, H_N / 128);
        proj_kernel<0><<<pg, 256, 0, stream>>>(q_low + xoff, WqT, bq, Qc, Mc, QSCALE);
        proj_kernel<0><<<pg, 256, 0, stream>>>(k_low + xoff, WkT, bk, Kc, Mc, 1.0f);
        proj_kernel<1><<<pg, 256, 0, stream>>>(v_low + xoff, WvT, bv, Vc, Mc, 1.0f);

        dim3 ag(C * NH_N, (S_N + 127) / 128);
        attn_kernel<<<ag, 256, 0, stream>>>(Qc, Kc, Vc, ctc);

        dim3 dg((Mc + 63) / 64, R_N / 64);
        dproj_kernel<<<dg, 256, 0, stream>>>(ctc, WoT, out + xoff, Mc);
    }
}

// Round 2
// 632.393 us; speedup vs baseline: 1.5838x; 1.1051x over previous
//
#include <hip/hip_runtime.h>
#include <hip/hip_bf16.h>
#include <math.h>

using short8   = __attribute__((ext_vector_type(8))) short;
using floatx4  = __attribute__((ext_vector_type(4))) float;
using floatx16 = __attribute__((ext_vector_type(16))) float;

#define B_N  32
#define S_N  1026
#define R_N  256
#define H_N  1024
#define NH_N 16
#define HD_N 64
#define SP_N 1088          // padded S for V^T rows: 17 * 64, pad cols zeroed once
#define KTILES 17          // SP_N / 64

__device__ __forceinline__ float bf2f(__hip_bfloat16 x) { return __bfloat162float(x); }
__device__ __forceinline__ __hip_bfloat16 f2bf(float x) { return __float2bfloat16(x); }

__device__ __forceinline__ float fast_exp2(float x) {
#if __has_builtin(__builtin_amdgcn_exp2f)
    return __builtin_amdgcn_exp2f(x);
#else
    return exp2f(x);
#endif
}

// pack two f32 -> one u32 of two bf16 (RNE), single instruction
__device__ __forceinline__ unsigned cvtpk(float lo, float hi_) {
    unsigned r;
    asm("v_cvt_pk_bf16_f32 %0, %1, %2" : "=v"(r) : "v"(lo), "v"(hi_));
    return r;
}

// async global->LDS, 16B per lane; LDS dest = uniform base + lane*16
__device__ __forceinline__ void gl_lds16(const void* g, void* l) {
    __builtin_amdgcn_global_load_lds(
        (const __attribute__((address_space(1))) unsigned int*)g,
        (__attribute__((address_space(3))) unsigned int*)l, 16, 0, 0);
}

// convert 8 fp32 (two float4) -> short8 of bf16
__device__ __forceinline__ short8 cvt8(const float* __restrict__ p) {
    floatx4 a = *(const floatx4*)p;
    floatx4 b = *(const floatx4*)(p + 4);
    short8 o;
    __hip_bfloat16* op = (__hip_bfloat16*)&o;
    op[0] = f2bf(a[0]); op[1] = f2bf(a[1]); op[2] = f2bf(a[2]); op[3] = f2bf(a[3]);
    op[4] = f2bf(b[0]); op[5] = f2bf(b[1]); op[6] = f2bf(b[2]); op[7] = f2bf(b[3]);
    return o;
}

// ---------------- LDS-tiled transpose + downcast: out[n*K + k] = bf16(in[k*N + n]) -----
// K, N multiples of 32. Coalesced fp32 reads, coalesced bf16 writes.
__global__ __launch_bounds__(256) void transpose_kernel(const float* __restrict__ in,
                                                        __hip_bfloat16* __restrict__ out,
                                                        int K, int N) {
    __shared__ __hip_bfloat16 t[32][33];
    const int k0 = blockIdx.x * 32, n0 = blockIdx.y * 32;
    const int tx = threadIdx.x & 31, ty = threadIdx.x >> 5;   // 32 x 8
#pragma unroll
    for (int j = 0; j < 32; j += 8)
        t[ty + j][tx] = f2bf(in[(size_t)(k0 + ty + j) * N + n0 + tx]);
    __syncthreads();
#pragma unroll
    for (int j = 0; j < 32; j += 8)
        out[(size_t)(n0 + ty + j) * K + k0 + tx] = t[tx][ty + j];
}

// ---------------- fused fp32 -> bf16 convert for q/k/v_low (one launch) ----------------
__global__ __launch_bounds__(256) void cvtx_kernel(
    const float* __restrict__ q, const float* __restrict__ k, const float* __restrict__ v,
    __hip_bfloat16* __restrict__ oq, __hip_bfloat16* __restrict__ ok,
    __hip_bfloat16* __restrict__ ov, int n8) {
    int idx = blockIdx.x * 256 + threadIdx.x;
    if (idx >= n8) return;
    const float* s = (blockIdx.y == 0) ? q : (blockIdx.y == 1) ? k : v;
    __hip_bfloat16* d = (blockIdx.y == 0) ? oq : (blockIdx.y == 1) ? ok : ov;
    *(short8*)(d + (size_t)idx * 8) = cvt8(s + (size_t)idx * 8);
}

// ---------------- zero the V^T pad columns [S_N, SP_N) once per launch ----------------
__global__ void padv_kernel(__hip_bfloat16* __restrict__ Vt, int total) {
    int idx = blockIdx.x * 256 + threadIdx.x;
    if (idx < total) {
        int p  = idx % (SP_N - S_N);
        int rd = idx / (SP_N - S_N);          // row index over C*NH*HD d-rows
        Vt[(size_t)rd * SP_N + S_N + p] = f2bf(0.f);
    }
}

// ---------------- up-projection, 128x128 tile, m97-style gload_lds staging -------------
// C[m,n] = oscale*(X[m,:] @ W[:,n] + bias[n]);  X bf16 [Mc,R], WT bf16 [H,R]
// MODE 0: out[((bl*NH + h)*S + s)*HD + d]    (Q, K layout)
// MODE 1: out[((bl*NH + h)*HD + d)*SP + s]   (V transposed layout, padded rows)
template <int MODE>
__global__ __launch_bounds__(256) void proj_kernel(
    const __hip_bfloat16* __restrict__ X,     // [Mc, R_N] bf16
    const __hip_bfloat16* __restrict__ WT,    // [H_N, R_N]  (W transposed, bf16)
    const float* __restrict__ bias,           // [H_N] fp32
    __hip_bfloat16* __restrict__ out, int Mc, float oscale) {
    __shared__ __hip_bfloat16 As[128][32];
    __shared__ __hip_bfloat16 Bs[128][32];
    const int tid  = threadIdx.x;
    const int wave = tid >> 6, lane = tid & 63;
    const int quad = lane >> 4, l16 = lane & 15;
    const int tm = blockIdx.x * 128, tn = blockIdx.y * 128;
    const int mw = (wave >> 1) * 64, nw = (wave & 1) * 64;
    const int lrow = lane >> 2, lchunk = lane & 3;   // staging: 16 rows x 4 chunks / instr

    floatx4 acc[4][4] = {};

    const int g0 = wave, g1 = wave + 4;
    int ra0 = tm + g0 * 16 + lrow; if (ra0 >= Mc) ra0 = Mc - 1;
    int ra1 = tm + g1 * 16 + lrow; if (ra1 >= Mc) ra1 = Mc - 1;
    const int rb0 = tn + g0 * 16 + lrow, rb1 = tn + g1 * 16 + lrow;

    for (int kk = 0; kk < R_N; kk += 32) {
        __syncthreads();
        gl_lds16(X  + (size_t)ra0 * R_N + kk + lchunk * 8, &As[g0 * 16][0]);
        gl_lds16(X  + (size_t)ra1 * R_N + kk + lchunk * 8, &As[g1 * 16][0]);
        gl_lds16(WT + (size_t)rb0 * R_N + kk + lchunk * 8, &Bs[g0 * 16][0]);
        gl_lds16(WT + (size_t)rb1 * R_N + kk + lchunk * 8, &Bs[g1 * 16][0]);
        __syncthreads();
        short8 af[4], bfr[4];
#pragma unroll
        for (int mb = 0; mb < 4; ++mb) af[mb]  = *(short8*)&As[mw + mb * 16 + l16][quad * 8];
#pragma unroll
        for (int nb = 0; nb < 4; ++nb) bfr[nb] = *(short8*)&Bs[nw + nb * 16 + l16][quad * 8];
#pragma unroll
        for (int mb = 0; mb < 4; ++mb)
#pragma unroll
            for (int nb = 0; nb < 4; ++nb) {
                if (MODE == 0)
                    acc[mb][nb] = __builtin_amdgcn_mfma_f32_16x16x32_bf16(af[mb], bfr[nb], acc[mb][nb], 0, 0, 0);
                else  // transposed product: C rows = n, cols = m (coalesced V^T store)
                    acc[mb][nb] = __builtin_amdgcn_mfma_f32_16x16x32_bf16(bfr[nb], af[mb], acc[mb][nb], 0, 0, 0);
            }
    }

#pragma unroll
    for (int mb = 0; mb < 4; ++mb)
#pragma unroll
        for (int nb = 0; nb < 4; ++nb)
#pragma unroll
            for (int r = 0; r < 4; ++r) {
                int m, n;
                if (MODE == 0) { m = tm + mw + mb * 16 + quad * 4 + r; n = tn + nw + nb * 16 + l16; }
                else           { n = tn + nw + nb * 16 + quad * 4 + r; m = tm + mw + mb * 16 + l16; }
                if (m >= Mc) continue;
                float v = oscale * (acc[mb][nb][r] + bias[n]);
                int bl = m / S_N, s = m - bl * S_N;
                int h = n >> 6, d = n & 63;
                size_t off = (MODE == 0)
                    ? ((size_t)((bl * NH_N + h) * S_N + s)) * HD_N + d
                    : ((size_t)((bl * NH_N + h) * HD_N + d)) * SP_N + s;
                out[off] = f2bf(v);
            }
}

// ---------------- flash attention: swapped QK^T (32x32x16), in-register softmax --------
__global__ __launch_bounds__(256, 3) void attn_kernel(
    const __hip_bfloat16* __restrict__ Qh,  // [C*NH, S, HD]  (pre-scaled by log2e/8)
    const __hip_bfloat16* __restrict__ Kh,  // [C*NH, S, HD]
    const __hip_bfloat16* __restrict__ Vt,  // [C*NH, HD, SP] (pad cols zeroed)
    __hip_bfloat16* __restrict__ ctx) {     // [C, S, NH*HD]
    __shared__ __hip_bfloat16 Kl[2][64][64];   // [buf][key][d], chunk^=(key&7)
    __shared__ __hip_bfloat16 Vl[2][64][64];   // [buf][d][key], chunk^=(d&7)

    const int bh  = blockIdx.x;
    const int q0  = blockIdx.y * 128;
    const int tid = threadIdx.x;
    const int wave = tid >> 6, lane = tid & 63;
    const int c = lane & 31, hi = lane >> 5, c7 = c & 7;
    const size_t base  = (size_t)bh * S_N * HD_N;
    const size_t vbase = (size_t)bh * HD_N * SP_N;

    // staging lane constants: lane covers (row lr, chunk lane&7) of an 8-row slab
    const int lr = lane >> 3;          // 0..7
    const int sc = (lane & 7) ^ lr;    // pre-swizzled source chunk ((row&7)==lr)

    // ---- Q B-frags in registers: lane holds Q[q0+wave*32+c][16*i + 8*hi + j] ----
    short8 qf[4];
    {
        int qrow = q0 + wave * 32 + c;
        if (qrow > S_N - 1) qrow = S_N - 1;            // dup row; outputs guarded
        const __hip_bfloat16* qp = Qh + base + (size_t)qrow * HD_N + hi * 8;
#pragma unroll
        for (int i = 0; i < 4; ++i) qf[i] = *(const short8*)(qp + 16 * i);
    }

    floatx16 oacc[2] = {};   // O[q (regs)][d = 32*db + c]
    float lsum = 0.f;        // partial row-sum for q=c (this hi-half's keys)

    auto stage = [&](int bb, int kt) {
#pragma unroll
        for (int j = 0; j < 2; ++j) {
            int r = 16 * wave + 8 * j + lr;            // tile row 0..63
            int krow = kt + r;
            if (krow > S_N - 1) krow = S_N - 1;        // dup; masked by key index
            gl_lds16(Kh + base + (size_t)krow * HD_N + sc * 8,
                     &Kl[bb][16 * wave + 8 * j][0]);
            gl_lds16(Vt + vbase + (size_t)r * SP_N + kt + sc * 8,
                     &Vl[bb][16 * wave + 8 * j][0]);
        }
    };

    stage(0, 0);
    __syncthreads();                                    // implies vmcnt(0) drain

    int bb = 0;
    for (int t = 0; t < KTILES; ++t) {
        const int kt = t * 64;
        if (t + 1 < KTILES) stage(bb ^ 1, kt + 64);     // prefetch next tile
        const bool last = (kt + 64 > S_N);

        short8 pa[2][2];                                // P A-frags [sub][16-key step]
#pragma unroll
        for (int sub = 0; sub < 2; ++sub) {
            // S^T = K_tile(32) x Q^T: lane col = q (=c), regs = key rows
            floatx16 sacc = {};
#pragma unroll
            for (int i = 0; i < 4; ++i) {
                short8 kf = *(const short8*)&Kl[bb][32 * sub + c][(((2 * i + hi) ^ c7) << 3)];
                sacc = __builtin_amdgcn_mfma_f32_32x32x16_bf16(kf, qf[i], sacc, 0, 0, 0);
            }
            float ps[16];
            if (!last) {
#pragma unroll
                for (int r = 0; r < 16; ++r) ps[r] = fast_exp2(sacc[r]);
            } else {
#pragma unroll
                for (int r = 0; r < 16; ++r) {
                    int key = kt + 32 * sub + (r & 3) + 8 * (r >> 2) + 4 * hi;
                    ps[r] = (key < S_N) ? fast_exp2(sacc[r]) : 0.f;
                }
            }
#pragma unroll
            for (int r = 0; r < 16; ++r) lsum += ps[r];
            // in-register repack: reg r holds key (r&3)+8*(r>>2)+4*hi; PV A-frag
            // needs keys 8*hi+j per 16-key step -> pair-pack + lane<->lane+32 swap
#pragma unroll
            for (int step = 0; step < 2; ++step) {
                unsigned w0 = cvtpk(ps[8 * step + 0], ps[8 * step + 1]);
                unsigned w1 = cvtpk(ps[8 * step + 2], ps[8 * step + 3]);
                unsigned w2 = cvtpk(ps[8 * step + 4], ps[8 * step + 5]);
                unsigned w3 = cvtpk(ps[8 * step + 6], ps[8 * step + 7]);
                asm("v_permlane32_swap_b32 %0, %1" : "+v"(w0), "+v"(w2));
                asm("v_permlane32_swap_b32 %0, %1" : "+v"(w1), "+v"(w3));
                union { unsigned u[4]; short8 s; } fu;
                fu.u[0] = w0; fu.u[1] = w1; fu.u[2] = w2; fu.u[3] = w3;
                pa[sub][step] = fu.s;
            }
        }

        // O += P @ V  (B-frag: V[key][d], col = d = 32*db + c)
#pragma unroll
        for (int db = 0; db < 2; ++db)
#pragma unroll
            for (int sub = 0; sub < 2; ++sub)
#pragma unroll
                for (int step = 0; step < 2; ++step) {
                    short8 vf = *(const short8*)
                        &Vl[bb][32 * db + c][((((sub * 2 + step) * 2 + hi) ^ c7) << 3)];
                    oacc[db] = __builtin_amdgcn_mfma_f32_32x32x16_bf16(pa[sub][step], vf, oacc[db], 0, 0, 0);
                }

        __syncthreads();    // prefetch landed (vmcnt0) + all waves done with buf bb
        bb ^= 1;
    }

    // combine the two hi-halves' partial sums; reciprocal once per q-row
    lsum += __shfl_xor(lsum, 32);
    float rs = 1.0f / lsum;

    const int bl = bh / NH_N, h = bh - bl * NH_N;
    const int srow0 = q0 + wave * 32;
#pragma unroll
    for (int r = 0; r < 16; ++r) {
        int q = (r & 3) + 8 * (r >> 2) + 4 * hi;       // O row of reg r
        float rr = __shfl(rs, q, 32);                  // rs lives at lane c==q (both halves)
        int s = srow0 + q;
        if (s < S_N) {
            size_t o = ((size_t)(bl * S_N + s)) * H_N + h * HD_N + c;
            ctx[o]      = f2bf(oacc[0][r] * rr);
            ctx[o + 32] = f2bf(oacc[1][r] * rr);
        }
    }
}

// ---------------- down-projection, 128x128 tile, gload_lds staging + exact gelu --------
__global__ __launch_bounds__(256) void dproj_kernel(
    const __hip_bfloat16* __restrict__ X,    // ctx [Mc, H_N] bf16
    const __hip_bfloat16* __restrict__ WT,   // WoT [R_N, H_N] bf16
    float* __restrict__ out,                 // [Mc, R_N] fp32
    int Mc) {
    __shared__ __hip_bfloat16 As[128][32];
    __shared__ __hip_bfloat16 Bs[128][32];
    const int tid  = threadIdx.x;
    const int wave = tid >> 6, lane = tid & 63;
    const int quad = lane >> 4, l16 = lane & 15;
    const int tm = blockIdx.x * 128, tn = blockIdx.y * 128;
    const int mw = (wave >> 1) * 64, nw = (wave & 1) * 64;
    const int lrow = lane >> 2, lchunk = lane & 3;

    floatx4 acc[4][4] = {};

    const int g0 = wave, g1 = wave + 4;
    int ra0 = tm + g0 * 16 + lrow; if (ra0 >= Mc) ra0 = Mc - 1;
    int ra1 = tm + g1 * 16 + lrow; if (ra1 >= Mc) ra1 = Mc - 1;
    const int rb0 = tn + g0 * 16 + lrow, rb1 = tn + g1 * 16 + lrow;

    for (int kk = 0; kk < H_N; kk += 32) {
        __syncthreads();
        gl_lds16(X  + (size_t)ra0 * H_N + kk + lchunk * 8, &As[g0 * 16][0]);
        gl_lds16(X  + (size_t)ra1 * H_N + kk + lchunk * 8, &As[g1 * 16][0]);
        gl_lds16(WT + (size_t)rb0 * H_N + kk + lchunk * 8, &Bs[g0 * 16][0]);
        gl_lds16(WT + (size_t)rb1 * H_N + kk + lchunk * 8, &Bs[g1 * 16][0]);
        __syncthreads();
        short8 af[4], bfr[4];
#pragma unroll
        for (int mb = 0; mb < 4; ++mb) af[mb]  = *(short8*)&As[mw + mb * 16 + l16][quad * 8];
#pragma unroll
        for (int nb = 0; nb < 4; ++nb) bfr[nb] = *(short8*)&Bs[nw + nb * 16 + l16][quad * 8];
#pragma unroll
        for (int mb = 0; mb < 4; ++mb)
#pragma unroll
            for (int nb = 0; nb < 4; ++nb)
                acc[mb][nb] = __builtin_amdgcn_mfma_f32_16x16x32_bf16(af[mb], bfr[nb], acc[mb][nb], 0, 0, 0);
    }

#pragma unroll
    for (int mb = 0; mb < 4; ++mb)
#pragma unroll
        for (int nb = 0; nb < 4; ++nb)
#pragma unroll
            for (int r = 0; r < 4; ++r) {
                int m = tm + mw + mb * 16 + quad * 4 + r;
                int n = tn + nw + nb * 16 + l16;
                if (m >= Mc) continue;
                float x = acc[mb][nb][r];
                float g = 0.5f * x * (1.0f + erff(x * 0.70710678118654752f));
                out[(size_t)m * R_N + n] = g;
            }
}

extern "C" void kernel_launch(void* const* d_in, const int* in_sizes, int n_in,
                              void* d_out, int out_size, void* d_ws, size_t ws_size,
                              hipStream_t stream) {
    const float* q_low = (const float*)d_in[0];
    const float* k_low = (const float*)d_in[1];
    const float* v_low = (const float*)d_in[2];
    const float* Wq    = (const float*)d_in[3];
    const float* bq    = (const float*)d_in[4];
    const float* Wk    = (const float*)d_in[5];
    const float* bk    = (const float*)d_in[6];
    const float* Wv    = (const float*)d_in[7];
    const float* bv    = (const float*)d_in[8];
    const float* Wo    = (const float*)d_in[9];
    float* out = (float*)d_out;
    (void)in_sizes; (void)n_in; (void)out_size;

    const float QSCALE = 0.125f * 1.44269504088896f;   // log2(e)/sqrt(HD)
    const size_t SZ_W = (size_t)H_N * R_N * 2;

    int C = 32;
    while (C > 1) {
        size_t qk = (size_t)C * NH_N * S_N * HD_N * 2;
        size_t vv = (size_t)C * NH_N * HD_N * SP_N * 2;
        size_t cx = (size_t)C * S_N * H_N * 2;
        if (4 * SZ_W + 2 * qk + vv + cx <= ws_size) break;
        C >>= 1;
    }

    char* ws = (char*)d_ws;
    const size_t SZ_QK = (size_t)C * NH_N * S_N * HD_N * 2;
    const size_t SZ_V  = (size_t)C * NH_N * HD_N * SP_N * 2;
    __hip_bfloat16* WqT = (__hip_bfloat16*)(ws);
    __hip_bfloat16* WkT = (__hip_bfloat16*)(ws + SZ_W);
    __hip_bfloat16* WvT = (__hip_bfloat16*)(ws + 2 * SZ_W);
    __hip_bfloat16* WoT = (__hip_bfloat16*)(ws + 3 * SZ_W);
    __hip_bfloat16* Qc  = (__hip_bfloat16*)(ws + 4 * SZ_W);
    __hip_bfloat16* Kc  = (__hip_bfloat16*)(ws + 4 * SZ_W + SZ_QK);
    __hip_bfloat16* Vc  = (__hip_bfloat16*)(ws + 4 * SZ_W + 2 * SZ_QK);
    __hip_bfloat16* ctc = (__hip_bfloat16*)(ws + 4 * SZ_W + 2 * SZ_QK + SZ_V);

    // Weight transposes: grid (K/32, N/32)
    {
        dim3 tg(R_N / 32, H_N / 32);
        transpose_kernel<<<tg, 256, 0, stream>>>(Wq, WqT, R_N, H_N);
        transpose_kernel<<<tg, 256, 0, stream>>>(Wk, WkT, R_N, H_N);
        transpose_kernel<<<tg, 256, 0, stream>>>(Wv, WvT, R_N, H_N);
        dim3 to(H_N / 32, R_N / 32);
        transpose_kernel<<<to, 256, 0, stream>>>(Wo, WoT, H_N, R_N);
    }

    // zero V^T pad columns once (Vc reused across chunks; proj never touches them)
    {
        int total = C * NH_N * HD_N * (SP_N - S_N);
        padv_kernel<<<(total + 255) / 256, 256, 0, stream>>>(Vc, total);
    }

    for (int c0 = 0; c0 < B_N; c0 += C) {
        const int Mc = C * S_N;
        const size_t xoff = (size_t)c0 * S_N * R_N;

        // bf16 copies of the low-rank activations, aliased onto ctc (live only
        // until attn overwrites ctc -- proj finishes reading them before that).
        __hip_bfloat16* Xq = ctc;
        __hip_bfloat16* Xk = ctc + (size_t)Mc * R_N;
        __hip_bfloat16* Xv = ctc + 2 * (size_t)Mc * R_N;
        {
            int n8 = Mc * R_N / 8;
            dim3 cg((n8 + 255) / 256, 3);
            cvtx_kernel<<<cg, 256, 0, stream>>>(q_low + xoff, k_low + xoff, v_low + xoff,
                                                Xq, Xk, Xv, n8);
        }

        dim3 pg((Mc + 127) / 128, H_N / 128);
        proj_kernel<0><<<pg, 256, 0, stream>>>(Xq, WqT, bq, Qc, Mc, QSCALE);
        proj_kernel<0><<<pg, 256, 0, stream>>>(Xk, WkT, bk, Kc, Mc, 1.0f);
        proj_kernel<1><<<pg, 256, 0, stream>>>(Xv, WvT, bv, Vc, Mc, 1.0f);

        dim3 ag(C * NH_N, (S_N + 127) / 128);
        attn_kernel<<<ag, 256, 0, stream>>>(Qc, Kc, Vc, ctc);

        dim3 dg((Mc + 127) / 128, R_N / 128);
        dproj_kernel<<<dg, 256, 0, stream>>>(ctc, WoT, out + xoff, Mc);
    }
}